// Round 7
// baseline (344.496 us; speedup 1.0000x reference)
//
#include <hip/hip_runtime.h>
#include <hip/hip_bf16.h>

#define SEQ    2048
#define BATCH  2
#define MTOK   4096
#define EMBED  1024
#define HEADS  16
#define HDIM   64
#define QKV3   3072
#define FFN    4096

typedef __attribute__((ext_vector_type(8))) short bf16x8;
typedef __attribute__((ext_vector_type(4))) float f32x4;
typedef __attribute__((ext_vector_type(16))) float f32x16;

static __device__ __forceinline__ unsigned short f2bf(float f) {
  union { float f; unsigned u; } x; x.f = f;
  unsigned r = x.u + 0x7FFFu + ((x.u >> 16) & 1u);
  return (unsigned short)(r >> 16);
}
static __device__ __forceinline__ float bf2f(unsigned short u) {
  union { unsigned u; float f; } x; x.u = ((unsigned)u) << 16; return x.f;
}
static __device__ __forceinline__ unsigned pk2bf(float a, float b) {
#if __has_builtin(__builtin_amdgcn_cvt_pk_bf16_f32)
  typedef __attribute__((ext_vector_type(2))) __bf16 bf16x2_t;
  union { bf16x2_t v; unsigned u; } x;
  x.v = __builtin_amdgcn_cvt_pk_bf16_f32(a, b);
  return x.u;
#else
  return ((unsigned)f2bf(a)) | (((unsigned)f2bf(b)) << 16);
#endif
}
static __device__ __forceinline__ float fexp2(float x) {
#if __has_builtin(__builtin_amdgcn_exp2f)
  return __builtin_amdgcn_exp2f(x);
#else
  return exp2f(x);
#endif
}
static __device__ __forceinline__ float frcp(float x) {
#if __has_builtin(__builtin_amdgcn_rcpf)
  return __builtin_amdgcn_rcpf(x);
#else
  return 1.0f / x;
#endif
}
// gelu(v) = v * sigmoid(1.5957691*(v + 0.044715 v^3)); sigmoid via exp2.
static __device__ __forceinline__ float fgelu(float v) {
  float t = v * v;
  float z = v * __builtin_fmaf(-0.1029456f, t, -2.3022650687f);
  return v * frcp(1.0f + fexp2(z));
}

// half-swap across the lane<32 / lane>=32 split:
//   lo_out = concat(a[0:32], b[0:32])   hi_out = concat(a[32:64], b[32:64])
static __device__ __forceinline__ void halfswap(unsigned a, unsigned b, int hi,
                                                unsigned& lo_out, unsigned& hi_out) {
#if __has_builtin(__builtin_amdgcn_permlane32_swap)
  typedef __attribute__((ext_vector_type(2))) unsigned uint2v;
  uint2v r = __builtin_amdgcn_permlane32_swap(a, b, false, false);
  lo_out = r[0];
  hi_out = r[1];
#else
  unsigned as = (unsigned)__shfl_xor((int)a, 32);
  unsigned bs = (unsigned)__shfl_xor((int)b, 32);
  lo_out = hi ? bs : a;
  hi_out = hi ? b : as;
#endif
}

// async global->LDS, 16B per lane; lds dest is wave-uniform base + lane*16
static __device__ __forceinline__ void gload16(const unsigned short* g, unsigned short* l) {
  __builtin_amdgcn_global_load_lds((const __attribute__((address_space(1))) void*)g,
                                   (__attribute__((address_space(3))) void*)l, 16, 0, 0);
}

#define MEMFENCE asm volatile("" ::: "memory")

// ---------------- fused weight transpose + fp32->bf16: Wt[n][k] = W[k][n] (all 4 weights)
struct TD { const float* W; unsigned short* T; int K, N, ntx, base; };
struct TD4 { TD d[4]; };

__global__ void transpose_all(TD4 td) {
  __shared__ float t[32][33];
  int bid = blockIdx.x;
  int i = 0;
  if (bid >= td.d[1].base) i = 1;
  if (bid >= td.d[2].base) i = 2;
  if (bid >= td.d[3].base) i = 3;
  const TD& D = td.d[i];
  int local = bid - D.base;
  int n0 = (local % D.ntx) * 32, k0 = (local / D.ntx) * 32;
  int tx = threadIdx.x, ty = threadIdx.y;  // block (32,8)
#pragma unroll
  for (int j = 0; j < 32; j += 8)
    t[ty + j][tx] = D.W[(size_t)(k0 + ty + j) * D.N + n0 + tx];
  __syncthreads();
#pragma unroll
  for (int j = 0; j < 32; j += 8)
    D.T[(size_t)(n0 + ty + j) * D.K + k0 + tx] = f2bf(t[tx][ty + j]);
}

// ---------------- layernorm (one token per block), fp32 in -> bf16 out
__global__ __launch_bounds__(256) void ln_kernel(const float* __restrict__ in,
                                                 const float* __restrict__ w,
                                                 const float* __restrict__ b,
                                                 unsigned short* __restrict__ out) {
  __shared__ float sh[4];
  int row = blockIdx.x, tid = threadIdx.x;
  const float4 v = ((const float4*)(in + (size_t)row * EMBED))[tid];
  float s = v.x + v.y + v.z + v.w;
#pragma unroll
  for (int off = 32; off; off >>= 1) s += __shfl_xor(s, off);
  if ((tid & 63) == 0) sh[tid >> 6] = s;
  __syncthreads();
  float mean = (sh[0] + sh[1] + sh[2] + sh[3]) * (1.0f / EMBED);
  __syncthreads();
  float dx = v.x - mean, dy = v.y - mean, dz = v.z - mean, dw = v.w - mean;
  float q = dx * dx + dy * dy + dz * dz + dw * dw;
#pragma unroll
  for (int off = 32; off; off >>= 1) q += __shfl_xor(q, off);
  if ((tid & 63) == 0) sh[tid >> 6] = q;
  __syncthreads();
  float var = (sh[0] + sh[1] + sh[2] + sh[3]) * (1.0f / EMBED);
  float rs = rsqrtf(var + 1e-5f);
  const float4 wv = ((const float4*)w)[tid];
  const float4 bv = ((const float4*)b)[tid];
  ushort4 o;
  o.x = f2bf(dx * rs * wv.x + bv.x);
  o.y = f2bf(dy * rs * wv.y + bv.y);
  o.z = f2bf(dz * rs * wv.z + bv.z);
  o.w = f2bf(dw * rs * wv.w + bv.w);
  ((ushort4*)(out + (size_t)row * EMBED))[tid] = o;
}

// ---------------- 256x256 8-phase GEMM (T3+T4+T2+T5), BK=64, dual K-tile slots.
// 8 waves (2M x 4N), 512 threads, LDS 128 KB -> 1 block/CU (2 waves/SIMD).
// Per iteration: 2 K-tiles (K += 128), 8 phases; phase = {pre-issued ds_reads ||
// 2 gload16 staging -> [publish: vmcnt(2)] -> barrier -> 16 MFMA (setprio) -> barrier}.
// Staging ledger: slot s holds K-tile t (t&1 == s). K-tile 2i+1 staged ph0-3 (2 loads/ph),
// published at ph4's vmcnt(2); K-tile 2i+2 staged ph4-7, published at next iter ph0's
// vmcnt(2). vmcnt(2) = own 2 just-issued loads remain; the published slot's 8 are older.
// Last-iter publishes use vmcnt(0). Row-chunk XOR swizzle on stage-source and read side.
// Epilogue: ACT -> fgelu; VSPLIT -> cols >= 2*EMBED go to vT (V transposed [bh*64+d][tok]).
template <int ACT, int VSPLIT>
__global__ __launch_bounds__(512, 2) void gemm256(const unsigned short* __restrict__ A,
                                                  const unsigned short* __restrict__ Wt,
                                                  const float* __restrict__ bias,
                                                  unsigned short* __restrict__ outB,
                                                  unsigned short* __restrict__ vT,
                                                  int M, int N, int K, int nblk) {
  __shared__ __align__(16) unsigned short As[2][256 * 64];  // 64 KB
  __shared__ __align__(16) unsigned short Bs[2][256 * 64];  // 64 KB
  const int tid = threadIdx.x;
  const int wave = tid >> 6, lane = tid & 63;
  const int quad = lane >> 4, ml = lane & 15;
  const int wr = wave >> 2, wc = wave & 3;  // 2M x 4N wave grid
  const int m0 = (blockIdx.x / nblk) * 256;
  const int n0 = (blockIdx.x % nblk) * 256;
  const int srow = lane >> 3;
  const int schunk = (lane & 7) ^ (srow & 7);
  // staging: wave stages its own 32-row band of A and of B per K-tile (4+4 gload16)
  const unsigned short* Ag = A  + (size_t)(m0 + wave * 32 + srow) * K + schunk * 8;
  const unsigned short* Bg = Wt + (size_t)(n0 + wave * 32 + srow) * K + schunk * 8;
  f32x4 acc[8][4];
#pragma unroll
  for (int i = 0; i < 8; i++)
#pragma unroll
    for (int j = 0; j < 4; j++) acc[i][j] = (f32x4){0.f, 0.f, 0.f, 0.f};

  // prologue: stage K-tile 0 -> slot 0 (8 gload16/wave)
#pragma unroll
  for (int g = 0; g < 4; g++) {
    gload16(Ag + (size_t)(g * 8) * K, &As[0][(wave * 32 + g * 8) * 64]);
    gload16(Bg + (size_t)(g * 8) * K, &Bs[0][(wave * 32 + g * 8) * 64]);
  }

  const int nit = K >> 7;  // 2 K-tiles per iteration
  for (int it = 0; it < nit; ++it) {
#pragma unroll
    for (int half = 0; half < 2; ++half) {
      const int rs = half;                 // slot being read this half
      const int ss = half ^ 1;             // slot being staged this half
      const int kst = 2 * it + 1 + half;   // K-tile being staged
      const bool doStage = (kst < 2 * nit);
      const unsigned short* Asl = &As[rs][0];
      const unsigned short* Bsl = &Bs[rs][0];
      bf16x8 bfr[4][2];
#pragma unroll
      for (int ph = 0; ph < 4; ++ph) {
        bf16x8 af[2][2];
        // pre-issue this phase's A-frag reads (data published at this half's ph0 barrier)
        if (ph > 0) {
#pragma unroll
          for (int mt2 = 0; mt2 < 2; ++mt2)
#pragma unroll
            for (int kk = 0; kk < 2; ++kk)
              af[mt2][kk] = *(const bf16x8*)&Asl[(wr * 128 + (ph * 2 + mt2) * 16 + ml) * 64 +
                                                ((kk * 4 + quad) ^ (ml & 7)) * 8];
        }
        // stage pair into slot ss (phases 0-1: A band halves; 2-3: B band halves)
        if (doStage) {
          if (ph < 2) {
            gload16(Ag + (size_t)((ph * 2) * 8) * K + kst * 64,
                    &As[ss][(wave * 32 + (ph * 2) * 8) * 64]);
            gload16(Ag + (size_t)((ph * 2 + 1) * 8) * K + kst * 64,
                    &As[ss][(wave * 32 + (ph * 2 + 1) * 8) * 64]);
          } else {
            gload16(Bg + (size_t)(((ph - 2) * 2) * 8) * K + kst * 64,
                    &Bs[ss][(wave * 32 + ((ph - 2) * 2) * 8) * 64]);
            gload16(Bg + (size_t)(((ph - 2) * 2 + 1) * 8) * K + kst * 64,
                    &Bs[ss][(wave * 32 + ((ph - 2) * 2 + 1) * 8) * 64]);
          }
        }
        if (ph == 0) {
          // publish slot rs: wait its 8 staging loads (own 2 newest may stay in flight)
          if (doStage) { asm volatile("s_waitcnt vmcnt(2)" ::: "memory"); }
          else         { asm volatile("s_waitcnt vmcnt(0)" ::: "memory"); }
          MEMFENCE; __builtin_amdgcn_s_barrier(); MEMFENCE;
          // now safe to read: B-frags for the whole half (8) + A quad0 (4)
#pragma unroll
          for (int nt = 0; nt < 4; ++nt)
#pragma unroll
            for (int kk = 0; kk < 2; ++kk)
              bfr[nt][kk] = *(const bf16x8*)&Bsl[(wc * 64 + nt * 16 + ml) * 64 +
                                                ((kk * 4 + quad) ^ (ml & 7)) * 8];
#pragma unroll
          for (int mt2 = 0; mt2 < 2; ++mt2)
#pragma unroll
            for (int kk = 0; kk < 2; ++kk)
              af[mt2][kk] = *(const bf16x8*)&Asl[(wr * 128 + mt2 * 16 + ml) * 64 +
                                                ((kk * 4 + quad) ^ (ml & 7)) * 8];
        } else {
          MEMFENCE; __builtin_amdgcn_s_barrier(); MEMFENCE;
        }
        __builtin_amdgcn_s_setprio(1);
#pragma unroll
        for (int mt2 = 0; mt2 < 2; ++mt2)
#pragma unroll
          for (int nt = 0; nt < 4; ++nt)
#pragma unroll
            for (int kk = 0; kk < 2; ++kk)
              acc[ph * 2 + mt2][nt] = __builtin_amdgcn_mfma_f32_16x16x32_bf16(
                  af[mt2][kk], bfr[nt][kk], acc[ph * 2 + mt2][nt], 0, 0, 0);
        __builtin_amdgcn_s_setprio(0);
        MEMFENCE; __builtin_amdgcn_s_barrier(); MEMFENCE;
      }
    }
  }
  // epilogue: bias (+gelu) + bf16 store; VSPLIT: V columns -> transposed vT
#pragma unroll
  for (int mt = 0; mt < 8; ++mt)
#pragma unroll
    for (int nt = 0; nt < 4; ++nt) {
      const int col0 = n0 + wc * 64 + nt * 16;
      const int row0 = m0 + wr * 128 + mt * 16;
      if (VSPLIT && col0 >= 2 * EMBED) {
        const int b = row0 >> 11, tok0 = row0 & (SEQ - 1);
        const int h = (col0 - 2 * EMBED) >> 6;
        const int dl = ((col0 - 2 * EMBED) & 63) + ml;
        float bia = bias[col0 + ml];
        ushort4 o;
        o.x = f2bf(acc[mt][nt][0] + bia);
        o.y = f2bf(acc[mt][nt][1] + bia);
        o.z = f2bf(acc[mt][nt][2] + bia);
        o.w = f2bf(acc[mt][nt][3] + bia);
        *(ushort4*)(vT + (size_t)((b * 16 + h) * 64 + dl) * SEQ + tok0 + quad * 4) = o;
      } else {
#pragma unroll
        for (int r = 0; r < 4; ++r) {
          int row = row0 + quad * 4 + r;
          int col = col0 + ml;
          float v = acc[mt][nt][r] + bias[col];
          if (ACT) v = fgelu(v);
          outB[(size_t)row * N + col] = f2bf(v);
        }
      }
    }
}

// ---------------- 128x64 NT GEMM, BK=64, XOR-swizzled LDS, XCD m-stripe grid.
// v3: 2-phase double-buffered prefetch (T3-min): grid shape-pinned at 2 blocks/CU,
// prefetch-before-compute + one barrier/iter reclaims exposed stage latency.
template <int RES, int OUTBF>
__global__ __launch_bounds__(256) void gemm64k(const unsigned short* __restrict__ A,
                                               const unsigned short* __restrict__ Wt,
                                               const float* __restrict__ bias,
                                               const float* __restrict__ res,
                                               unsigned short* __restrict__ outB,
                                               float* __restrict__ outF,
                                               int M, int N, int K, int nblk) {
  __shared__ __align__(16) unsigned short As[2][128 * 64];  // 32 KB
  __shared__ __align__(16) unsigned short Bs[2][64 * 64];   // 16 KB
  const int tid = threadIdx.x;
  const int wave = tid >> 6, lane = tid & 63;
  const int quad = lane >> 4, ml = lane & 15;
  const int wr = wave >> 1, wc = wave & 1;
  const int xcd = blockIdx.x & 7, idx = blockIdx.x >> 3;
  const int mPerXcd = (gridDim.x >> 3) / nblk;
  const int m0 = (xcd * mPerXcd + idx / nblk) * 128;
  const int n0 = (idx % nblk) * 64;
  const int srow = lane >> 3;
  const int schunk = (lane & 7) ^ (srow & 7);
  const unsigned short* Ag = A + (size_t)(m0 + wave * 32 + srow) * K + schunk * 8;
  const unsigned short* Bg = Wt + (size_t)(n0 + wave * 16 + srow) * K + schunk * 8;
  f32x4 acc[4][2];
#pragma unroll
  for (int i = 0; i < 4; i++) { acc[i][0] = (f32x4){0.f,0.f,0.f,0.f}; acc[i][1] = acc[i][0]; }
  {
    unsigned short* AsW = &As[0][wave * 2048];
    unsigned short* BsW = &Bs[0][wave * 1024];
    gload16(Ag, AsW);
    gload16(Ag + (size_t)8 * K,  AsW + 512);
    gload16(Ag + (size_t)16 * K, AsW + 1024);
    gload16(Ag + (size_t)24 * K, AsW + 1536);
    gload16(Bg, BsW);
    gload16(Bg + (size_t)8 * K,  BsW + 512);
    Ag += 64; Bg += 64;
  }
  __syncthreads();
  const int nk = K >> 6;
  for (int kk = 0; kk < nk; ++kk) {
    const int cur = kk & 1;
    if (kk + 1 < nk) {
      unsigned short* AsW = &As[cur ^ 1][wave * 2048];
      unsigned short* BsW = &Bs[cur ^ 1][wave * 1024];
      gload16(Ag, AsW);
      gload16(Ag + (size_t)8 * K,  AsW + 512);
      gload16(Ag + (size_t)16 * K, AsW + 1024);
      gload16(Ag + (size_t)24 * K, AsW + 1536);
      gload16(Bg, BsW);
      gload16(Bg + (size_t)8 * K,  BsW + 512);
      Ag += 64; Bg += 64;
    }
#pragma unroll
    for (int kh = 0; kh < 2; kh++) {
      const int ch = ((kh * 4 + quad) ^ (ml & 7)) * 8;
      bf16x8 af[4], bfr[2];
#pragma unroll
      for (int mt = 0; mt < 4; mt++)
        af[mt] = *(const bf16x8*)&As[cur][(wr * 64 + mt * 16 + ml) * 64 + ch];
#pragma unroll
      for (int nt = 0; nt < 2; nt++)
        bfr[nt] = *(const bf16x8*)&Bs[cur][(wc * 32 + nt * 16 + ml) * 64 + ch];
#pragma unroll
      for (int mt = 0; mt < 4; mt++)
#pragma unroll
        for (int nt = 0; nt < 2; nt++)
          acc[mt][nt] = __builtin_amdgcn_mfma_f32_16x16x32_bf16(af[mt], bfr[nt], acc[mt][nt], 0, 0, 0);
    }
    __syncthreads();
  }
#pragma unroll
  for (int mt = 0; mt < 4; mt++)
#pragma unroll
    for (int nt = 0; nt < 2; nt++)
#pragma unroll
      for (int r = 0; r < 4; r++) {
        int row = m0 + wr * 64 + mt * 16 + quad * 4 + r;
        int col = n0 + wc * 32 + nt * 16 + ml;
        float v = acc[mt][nt][r] + bias[col];
        if (RES) v += res[(size_t)row * N + col];
        if (OUTBF)
          outB[(size_t)row * N + col] = f2bf(v);
        else
          outF[(size_t)row * N + col] = v;
      }
}

// ---------------- flash attention v4: 32x32x16 MFMA + in-reg softmax + KEY-SPLIT waves.
// (unchanged — 63.4 us, near its current-structure ceiling)
__global__ __launch_bounds__(256, 4) void attn_kernel(const unsigned short* __restrict__ qkv,
                                                      const unsigned short* __restrict__ vT,
                                                      unsigned short* __restrict__ attn) {
  __shared__ __align__(16) unsigned short Ks[2][64 * 64];  // 16 KB
  __shared__ __align__(16) unsigned short Vs[2][64 * 64];  // 16 KB
  const int tid = threadIdx.x, wave = tid >> 6, lane = tid & 63;
  const int l31 = lane & 31, hi = lane >> 5;
  const int qs = wave & 1, kh = wave >> 1;
  const int bh = blockIdx.x, b = bh >> 4, h = bh & 15;   // bh = fast grid axis
  const int q0w = blockIdx.y * 64 + qs * 32;
  const float qscale = 0.18033688011112042f;  // 0.125 * log2(e)
  const int sw = l31 & 7;

  const unsigned short* qrow = qkv + (size_t)(b * SEQ + q0w + l31) * QKV3 + h * HDIM;
  bf16x8 bq[4];
#pragma unroll
  for (int s = 0; s < 4; s++) {
    bq[s] = *(const bf16x8*)(qrow + s * 16 + hi * 8);
#pragma unroll
    for (int j = 0; j < 8; j++)
      bq[s][j] = (short)f2bf(bf2f((unsigned short)bq[s][j]) * qscale);
  }
  bf16x8 ones;
#pragma unroll
  for (int j = 0; j < 8; j++) ones[j] = (short)0x3F80;  // bf16 1.0

  f32x16 zz;
#pragma unroll
  for (int i = 0; i < 16; i++) zz[i] = 0.f;
  f32x16 O0 = zz, O1 = zz, lsum = zz;

  const int skey = lane >> 3;
  const int schunk8 = ((lane & 7) ^ (skey & 7)) * 8;
  const unsigned short* kbase =
      qkv + (size_t)(b * SEQ + wave * 16 + skey) * QKV3 + EMBED + h * HDIM + schunk8;
  const unsigned short* vbase =
      vT + (size_t)(bh * 64 + wave * 16 + skey) * SEQ + schunk8;

  gload16(kbase, &Ks[0][wave * 1024]);
  gload16(kbase + (size_t)8 * QKV3, &Ks[0][wave * 1024] + 512);
  gload16(vbase, &Vs[0][wave * 1024]);
  gload16(vbase + (size_t)8 * SEQ, &Vs[0][wave * 1024] + 512);
  __syncthreads();

  const int krow0 = kh * 32;
  for (int kti = 0; kti < SEQ / 64; ++kti) {
    const int cur = kti & 1;
    if (kti + 1 < SEQ / 64) {
      const int kt = (kti + 1) * 64;
      unsigned short* kd = &Ks[cur ^ 1][wave * 1024];
      unsigned short* vd = &Vs[cur ^ 1][wave * 1024];
      gload16(kbase + (size_t)kt * QKV3, kd);
      gload16(kbase + (size_t)(kt + 8) * QKV3, kd + 512);
      gload16(vbase + kt, vd);
      gload16(vbase + kt + (size_t)8 * SEQ, vd + 512);
    }
    const unsigned short* Kc = &Ks[cur][0];
    const unsigned short* Vc = &Vs[cur][0];

    f32x16 St = zz;
#pragma unroll
    for (int s = 0; s < 4; s++) {
      bf16x8 ak = *(const bf16x8*)&Kc[(krow0 + l31) * 64 + ((2 * s + hi) ^ sw) * 8];
      St = __builtin_amdgcn_mfma_f32_32x32x16_bf16(ak, bq[s], St, 0, 0, 0);
    }

    unsigned W0[4], W1[4];
#pragma unroll
    for (int g = 0; g < 4; g++) {
      W0[g] = pk2bf(fexp2(St[4 * g]), fexp2(St[4 * g + 1]));
      W1[g] = pk2bf(fexp2(St[4 * g + 2]), fexp2(St[4 * g + 3]));
    }

    bf16x8 pa[2];
#pragma unroll
    for (int ks = 0; ks < 2; ks++) {
      const int g0 = 2 * ks, g1 = g0 + 1;
      unsigned w0, w1, w2, w3;
      halfswap(W0[g0], W0[g1], hi, w0, w2);
      halfswap(W1[g0], W1[g1], hi, w1, w3);
      union { unsigned u[4]; bf16x8 v; } pw;
      pw.u[0] = w0; pw.u[1] = w1; pw.u[2] = w2; pw.u[3] = w3;
      pa[ks] = pw.v;
    }

    __builtin_amdgcn_s_setprio(1);
    lsum = __builtin_amdgcn_mfma_f32_32x32x16_bf16(pa[0], ones, lsum, 0, 0, 0);
    lsum = __builtin_amdgcn_mfma_f32_32x32x16_bf16(pa[1], ones, lsum, 0, 0, 0);
#pragma unroll
    for (int ks = 0; ks < 2; ks++) {
      const int ch = kh * 4 + ks * 2 + hi;
      bf16x8 bv0 = *(const bf16x8*)&Vc[l31 * 64 + (ch ^ sw) * 8];
      bf16x8 bv1 = *(const bf16x8*)&Vc[(32 + l31) * 64 + (ch ^ sw) * 8];
      O0 = __builtin_amdgcn_mfma_f32_32x32x16_bf16(pa[ks], bv0, O0, 0, 0, 0);
      O1 = __builtin_amdgcn_mfma_f32_32x32x16_bf16(pa[ks], bv1, O1, 0, 0, 0);
    }
    __builtin_amdgcn_s_setprio(0);
    __syncthreads();
  }

  if (kh == 1) {
    float* sc = qs ? (float*)&Vs[0][0] : (float*)&Ks[0][0];
#pragma unroll
    for (int r = 0; r < 16; r++) {
      sc[lane * 48 + r]      = lsum[r];
      sc[lane * 48 + 16 + r] = O0[r];
      sc[lane * 48 + 32 + r] = O1[r];
    }
  }
  __syncthreads();
  if (kh == 0) {
    const float* sc = qs ? (const float*)&Vs[0][0] : (const float*)&Ks[0][0];
#pragma unroll
    for (int r = 0; r < 16; r++) {
      lsum[r] += sc[lane * 48 + r];
      O0[r]   += sc[lane * 48 + 16 + r];
      O1[r]   += sc[lane * 48 + 32 + r];
    }
#pragma unroll
    for (int r = 0; r < 16; r++) {
      const int qr = (r & 3) + 8 * (r >> 2) + 4 * hi;
      float inv = 1.0f / lsum[r];
      size_t g = (size_t)(b * SEQ + q0w + qr) * EMBED + h * HDIM + l31;
      attn[g]      = f2bf(O0[r] * inv);
      attn[g + 32] = f2bf(O1[r] * inv);
    }
  }
}

extern "C" void kernel_launch(void* const* d_in, const int* in_sizes, int n_in,
                              void* d_out, int out_size, void* d_ws, size_t ws_size,
                              hipStream_t stream) {
  const float* x      = (const float*)d_in[0];
  const float* ln1_w  = (const float*)d_in[1];
  const float* ln1_b  = (const float*)d_in[2];
  const float* ln2_w  = (const float*)d_in[3];
  const float* ln2_b  = (const float*)d_in[4];
  const float* qkv_w  = (const float*)d_in[5];
  const float* qkv_b  = (const float*)d_in[6];
  const float* proj_w = (const float*)d_in[7];
  const float* proj_b = (const float*)d_in[8];
  const float* fc1_w  = (const float*)d_in[9];
  const float* fc1_b  = (const float*)d_in[10];
  const float* fc2_w  = (const float*)d_in[11];
  const float* fc2_b  = (const float*)d_in[12];
  float* out = (float*)d_out;
  char* wsb = (char*)d_ws;
  unsigned short* lnbuf  = (unsigned short*)(wsb + 0);
  unsigned short* qkvb   = (unsigned short*)(wsb + 8388608);
  unsigned short* attnb  = (unsigned short*)(wsb + 33554432);
  unsigned short* vTb    = (unsigned short*)(wsb + 41943040);
  unsigned short* actb   = (unsigned short*)(wsb + 33554432);
  float*          h1     = (float*)(wsb + 67108864);
  unsigned short* qkvWt  = (unsigned short*)(wsb + 83886080);
  unsigned short* projWt = (unsigned short*)(wsb + 90177536);
  unsigned short* fc1Wt  = (unsigned short*)(wsb + 92274688);
  unsigned short* fc2Wt  = (unsigned short*)(wsb + 100663296);

  TD4 td;
  td.d[0] = {qkv_w,  qkvWt,  1024, 3072,  96, 0};
  td.d[1] = {proj_w, projWt, 1024, 1024,  32, 3072};
  td.d[2] = {fc1_w,  fc1Wt,  1024, 4096, 128, 4096};
  td.d[3] = {fc2_w,  fc2Wt,  4096, 1024,  32, 8192};
  transpose_all<<<12288, dim3(32, 8), 0, stream>>>(td);

  ln_kernel<<<MTOK, 256, 0, stream>>>(x, ln1_w, ln1_b, lnbuf);
  gemm256<0, 1><<<192, 512, 0, stream>>>(
      lnbuf, qkvWt, qkv_b, qkvb, vTb, MTOK, QKV3, EMBED, 12);
  attn_kernel<<<dim3(32, 32), 256, 0, stream>>>(qkvb, vTb, attnb);
  gemm64k<1, 0><<<512, 256, 0, stream>>>(
      attnb, projWt, proj_b, x, nullptr, h1, MTOK, EMBED, EMBED, 16);
  ln_kernel<<<MTOK, 256, 0, stream>>>(h1, ln2_w, ln2_b, lnbuf);
  gemm256<1, 0><<<256, 512, 0, stream>>>(
      lnbuf, fc1Wt, fc1_b, actb, nullptr, MTOK, FFN, EMBED, 16);
  gemm64k<1, 0><<<512, 256, 0, stream>>>(
      actb, fc2Wt, fc2_b, h1, nullptr, out, MTOK, EMBED, FFN, 16);
}

// Round 8
// 342.453 us; speedup vs baseline: 1.0060x; 1.0060x over previous
//
#include <hip/hip_runtime.h>
#include <hip/hip_bf16.h>

#define SEQ    2048
#define BATCH  2
#define MTOK   4096
#define EMBED  1024
#define HEADS  16
#define HDIM   64
#define QKV3   3072
#define FFN    4096

typedef __attribute__((ext_vector_type(8))) short bf16x8;
typedef __attribute__((ext_vector_type(4))) float f32x4;
typedef __attribute__((ext_vector_type(16))) float f32x16;

static __device__ __forceinline__ unsigned short f2bf(float f) {
  union { float f; unsigned u; } x; x.f = f;
  unsigned r = x.u + 0x7FFFu + ((x.u >> 16) & 1u);
  return (unsigned short)(r >> 16);
}
static __device__ __forceinline__ float bf2f(unsigned short u) {
  union { unsigned u; float f; } x; x.u = ((unsigned)u) << 16; return x.f;
}
static __device__ __forceinline__ unsigned pk2bf(float a, float b) {
#if __has_builtin(__builtin_amdgcn_cvt_pk_bf16_f32)
  typedef __attribute__((ext_vector_type(2))) __bf16 bf16x2_t;
  union { bf16x2_t v; unsigned u; } x;
  x.v = __builtin_amdgcn_cvt_pk_bf16_f32(a, b);
  return x.u;
#else
  return ((unsigned)f2bf(a)) | (((unsigned)f2bf(b)) << 16);
#endif
}
static __device__ __forceinline__ float fexp2(float x) {
#if __has_builtin(__builtin_amdgcn_exp2f)
  return __builtin_amdgcn_exp2f(x);
#else
  return exp2f(x);
#endif
}
static __device__ __forceinline__ float frcp(float x) {
#if __has_builtin(__builtin_amdgcn_rcpf)
  return __builtin_amdgcn_rcpf(x);
#else
  return 1.0f / x;
#endif
}
// gelu(v) = v * sigmoid(1.5957691*(v + 0.044715 v^3)); sigmoid via exp2.
static __device__ __forceinline__ float fgelu(float v) {
  float t = v * v;
  float z = v * __builtin_fmaf(-0.1029456f, t, -2.3022650687f);
  return v * frcp(1.0f + fexp2(z));
}

// half-swap across the lane<32 / lane>=32 split:
//   lo_out = concat(a[0:32], b[0:32])   hi_out = concat(a[32:64], b[32:64])
static __device__ __forceinline__ void halfswap(unsigned a, unsigned b, int hi,
                                                unsigned& lo_out, unsigned& hi_out) {
#if __has_builtin(__builtin_amdgcn_permlane32_swap)
  typedef __attribute__((ext_vector_type(2))) unsigned uint2v;
  uint2v r = __builtin_amdgcn_permlane32_swap(a, b, false, false);
  lo_out = r[0];
  hi_out = r[1];
#else
  unsigned as = (unsigned)__shfl_xor((int)a, 32);
  unsigned bs = (unsigned)__shfl_xor((int)b, 32);
  lo_out = hi ? bs : a;
  hi_out = hi ? b : as;
#endif
}

// async global->LDS, 16B per lane; lds dest is wave-uniform base + lane*16
static __device__ __forceinline__ void gload16(const unsigned short* g, unsigned short* l) {
  __builtin_amdgcn_global_load_lds((const __attribute__((address_space(1))) void*)g,
                                   (__attribute__((address_space(3))) void*)l, 16, 0, 0);
}

#define MEMFENCE asm volatile("" ::: "memory")

// ---------------- fused weight transpose + fp32->bf16: Wt[n][k] = W[k][n] (all 4 weights)
struct TD { const float* W; unsigned short* T; int K, N, ntx, base; };
struct TD4 { TD d[4]; };

__global__ void transpose_all(TD4 td) {
  __shared__ float t[32][33];
  int bid = blockIdx.x;
  int i = 0;
  if (bid >= td.d[1].base) i = 1;
  if (bid >= td.d[2].base) i = 2;
  if (bid >= td.d[3].base) i = 3;
  const TD& D = td.d[i];
  int local = bid - D.base;
  int n0 = (local % D.ntx) * 32, k0 = (local / D.ntx) * 32;
  int tx = threadIdx.x, ty = threadIdx.y;  // block (32,8)
#pragma unroll
  for (int j = 0; j < 32; j += 8)
    t[ty + j][tx] = D.W[(size_t)(k0 + ty + j) * D.N + n0 + tx];
  __syncthreads();
#pragma unroll
  for (int j = 0; j < 32; j += 8)
    D.T[(size_t)(n0 + ty + j) * D.K + k0 + tx] = f2bf(t[tx][ty + j]);
}

// ---------------- layernorm (one token per block), fp32 in -> bf16 out
__global__ __launch_bounds__(256) void ln_kernel(const float* __restrict__ in,
                                                 const float* __restrict__ w,
                                                 const float* __restrict__ b,
                                                 unsigned short* __restrict__ out) {
  __shared__ float sh[4];
  int row = blockIdx.x, tid = threadIdx.x;
  const float4 v = ((const float4*)(in + (size_t)row * EMBED))[tid];
  float s = v.x + v.y + v.z + v.w;
#pragma unroll
  for (int off = 32; off; off >>= 1) s += __shfl_xor(s, off);
  if ((tid & 63) == 0) sh[tid >> 6] = s;
  __syncthreads();
  float mean = (sh[0] + sh[1] + sh[2] + sh[3]) * (1.0f / EMBED);
  __syncthreads();
  float dx = v.x - mean, dy = v.y - mean, dz = v.z - mean, dw = v.w - mean;
  float q = dx * dx + dy * dy + dz * dz + dw * dw;
#pragma unroll
  for (int off = 32; off; off >>= 1) q += __shfl_xor(q, off);
  if ((tid & 63) == 0) sh[tid >> 6] = q;
  __syncthreads();
  float var = (sh[0] + sh[1] + sh[2] + sh[3]) * (1.0f / EMBED);
  float rs = rsqrtf(var + 1e-5f);
  const float4 wv = ((const float4*)w)[tid];
  const float4 bv = ((const float4*)b)[tid];
  ushort4 o;
  o.x = f2bf(dx * rs * wv.x + bv.x);
  o.y = f2bf(dy * rs * wv.y + bv.y);
  o.z = f2bf(dz * rs * wv.z + bv.z);
  o.w = f2bf(dw * rs * wv.w + bv.w);
  ((ushort4*)(out + (size_t)row * EMBED))[tid] = o;
}

// ---------------- 128x128 NT bf16 GEMM, BK=64, XOR-swizzled LDS (128B rows),
// plain n-fastest block order (XCD x statically owns n === x mod 8 -> B slice L2-resident).
// (QKV engine — round-7 gemm256@192 regressed, reverted to this proven config.)
template <int ACT, int OUTBF, int VSPLIT>
__global__ __launch_bounds__(256) void gemmBig(const unsigned short* __restrict__ A,
                                               const unsigned short* __restrict__ Wt,
                                               const float* __restrict__ bias,
                                               unsigned short* __restrict__ outB,
                                               float* __restrict__ outF,
                                               unsigned short* __restrict__ vT,
                                               int M, int N, int K, int nblk) {
  __shared__ __align__(16) unsigned short As[128 * 64];  // 16 KB
  __shared__ __align__(16) unsigned short Bs[128 * 64];  // 16 KB
  const int tid = threadIdx.x;
  const int wave = tid >> 6, lane = tid & 63;
  const int quad = lane >> 4, ml = lane & 15;
  const int wr = wave >> 1, wc = wave & 1;
  const int m0 = (blockIdx.x / nblk) * 128;
  const int n0 = (blockIdx.x % nblk) * 128;
  const int srow = lane >> 3;
  const int schunk = (lane & 7) ^ (srow & 7);
  const unsigned short* Ag = A + (size_t)(m0 + wave * 32 + srow) * K + schunk * 8;
  const unsigned short* Bg = Wt + (size_t)(n0 + wave * 32 + srow) * K + schunk * 8;
  unsigned short* AsW = &As[wave * 2048];
  unsigned short* BsW = &Bs[wave * 2048];
  f32x4 acc[4][4];
#pragma unroll
  for (int i = 0; i < 4; i++)
#pragma unroll
    for (int j = 0; j < 4; j++) acc[i][j] = (f32x4){0.f, 0.f, 0.f, 0.f};
  for (int k0 = 0; k0 < K; k0 += 64) {
    __syncthreads();
#pragma unroll
    for (int t = 0; t < 4; t++) {
      gload16(Ag + (size_t)(8 * t) * K, AsW + 512 * t);
      gload16(Bg + (size_t)(8 * t) * K, BsW + 512 * t);
    }
    Ag += 64; Bg += 64;
    __syncthreads();
#pragma unroll
    for (int kh = 0; kh < 2; kh++) {
      const int ch = ((kh * 4 + quad) ^ (ml & 7)) * 8;
      bf16x8 af[4], bfr[4];
#pragma unroll
      for (int mt = 0; mt < 4; mt++)
        af[mt] = *(const bf16x8*)&As[(wr * 64 + mt * 16 + ml) * 64 + ch];
#pragma unroll
      for (int nt = 0; nt < 4; nt++)
        bfr[nt] = *(const bf16x8*)&Bs[(wc * 64 + nt * 16 + ml) * 64 + ch];
#pragma unroll
      for (int mt = 0; mt < 4; mt++)
#pragma unroll
        for (int nt = 0; nt < 4; nt++)
          acc[mt][nt] = __builtin_amdgcn_mfma_f32_16x16x32_bf16(af[mt], bfr[nt], acc[mt][nt], 0, 0, 0);
    }
  }
#pragma unroll
  for (int mt = 0; mt < 4; mt++)
#pragma unroll
    for (int nt = 0; nt < 4; nt++) {
      const int col0 = n0 + wc * 64 + nt * 16;
      const int row0 = m0 + wr * 64 + mt * 16;
      if (VSPLIT && col0 >= 2 * EMBED) {
        const int b = row0 >> 11, tok0 = row0 & (SEQ - 1);
        const int h = (col0 - 2 * EMBED) >> 6;
        const int dl = ((col0 - 2 * EMBED) & 63) + ml;
        float bia = bias[col0 + ml];
        ushort4 o;
        o.x = f2bf(acc[mt][nt][0] + bia);
        o.y = f2bf(acc[mt][nt][1] + bia);
        o.z = f2bf(acc[mt][nt][2] + bia);
        o.w = f2bf(acc[mt][nt][3] + bia);
        *(ushort4*)(vT + (size_t)((b * 16 + h) * 64 + dl) * SEQ + tok0 + quad * 4) = o;
      } else {
#pragma unroll
        for (int r = 0; r < 4; r++) {
          int row = row0 + quad * 4 + r;
          int col = col0 + ml;
          float v = acc[mt][nt][r] + bias[col];
          if (ACT) v = fgelu(v);
          if (OUTBF)
            outB[(size_t)row * N + col] = f2bf(v);
          else
            outF[(size_t)row * N + col] = v;
        }
      }
    }
}

// ---------------- 256x256 8-phase GEMM (T3+T4+T2+T5), BK=64, dual K-tile slots.
// (FC1 engine — exact-CU-fill 256 blocks; proven +4 us over 128^2 in round 6.)
template <int ACT, int VSPLIT>
__global__ __launch_bounds__(512, 2) void gemm256(const unsigned short* __restrict__ A,
                                                  const unsigned short* __restrict__ Wt,
                                                  const float* __restrict__ bias,
                                                  unsigned short* __restrict__ outB,
                                                  unsigned short* __restrict__ vT,
                                                  int M, int N, int K, int nblk) {
  __shared__ __align__(16) unsigned short As[2][256 * 64];  // 64 KB
  __shared__ __align__(16) unsigned short Bs[2][256 * 64];  // 64 KB
  const int tid = threadIdx.x;
  const int wave = tid >> 6, lane = tid & 63;
  const int quad = lane >> 4, ml = lane & 15;
  const int wr = wave >> 2, wc = wave & 3;  // 2M x 4N wave grid
  const int m0 = (blockIdx.x / nblk) * 256;
  const int n0 = (blockIdx.x % nblk) * 256;
  const int srow = lane >> 3;
  const int schunk = (lane & 7) ^ (srow & 7);
  const unsigned short* Ag = A  + (size_t)(m0 + wave * 32 + srow) * K + schunk * 8;
  const unsigned short* Bg = Wt + (size_t)(n0 + wave * 32 + srow) * K + schunk * 8;
  f32x4 acc[8][4];
#pragma unroll
  for (int i = 0; i < 8; i++)
#pragma unroll
    for (int j = 0; j < 4; j++) acc[i][j] = (f32x4){0.f, 0.f, 0.f, 0.f};

  // prologue: stage K-tile 0 -> slot 0 (8 gload16/wave)
#pragma unroll
  for (int g = 0; g < 4; g++) {
    gload16(Ag + (size_t)(g * 8) * K, &As[0][(wave * 32 + g * 8) * 64]);
    gload16(Bg + (size_t)(g * 8) * K, &Bs[0][(wave * 32 + g * 8) * 64]);
  }

  const int nit = K >> 7;  // 2 K-tiles per iteration
  for (int it = 0; it < nit; ++it) {
#pragma unroll
    for (int half = 0; half < 2; ++half) {
      const int rs = half;                 // slot being read this half
      const int ss = half ^ 1;             // slot being staged this half
      const int kst = 2 * it + 1 + half;   // K-tile being staged
      const bool doStage = (kst < 2 * nit);
      const unsigned short* Asl = &As[rs][0];
      const unsigned short* Bsl = &Bs[rs][0];
      bf16x8 bfr[4][2];
#pragma unroll
      for (int ph = 0; ph < 4; ++ph) {
        bf16x8 af[2][2];
        // pre-issue this phase's A-frag reads (data published at this half's ph0 barrier)
        if (ph > 0) {
#pragma unroll
          for (int mt2 = 0; mt2 < 2; ++mt2)
#pragma unroll
            for (int kk = 0; kk < 2; ++kk)
              af[mt2][kk] = *(const bf16x8*)&Asl[(wr * 128 + (ph * 2 + mt2) * 16 + ml) * 64 +
                                                ((kk * 4 + quad) ^ (ml & 7)) * 8];
        }
        // stage pair into slot ss (phases 0-1: A band halves; 2-3: B band halves)
        if (doStage) {
          if (ph < 2) {
            gload16(Ag + (size_t)((ph * 2) * 8) * K + kst * 64,
                    &As[ss][(wave * 32 + (ph * 2) * 8) * 64]);
            gload16(Ag + (size_t)((ph * 2 + 1) * 8) * K + kst * 64,
                    &As[ss][(wave * 32 + (ph * 2 + 1) * 8) * 64]);
          } else {
            gload16(Bg + (size_t)(((ph - 2) * 2) * 8) * K + kst * 64,
                    &Bs[ss][(wave * 32 + ((ph - 2) * 2) * 8) * 64]);
            gload16(Bg + (size_t)(((ph - 2) * 2 + 1) * 8) * K + kst * 64,
                    &Bs[ss][(wave * 32 + ((ph - 2) * 2 + 1) * 8) * 64]);
          }
        }
        if (ph == 0) {
          // publish slot rs: wait its 8 staging loads (own 2 newest may stay in flight)
          if (doStage) { asm volatile("s_waitcnt vmcnt(2)" ::: "memory"); }
          else         { asm volatile("s_waitcnt vmcnt(0)" ::: "memory"); }
          MEMFENCE; __builtin_amdgcn_s_barrier(); MEMFENCE;
          // now safe to read: B-frags for the whole half (8) + A quad0 (4)
#pragma unroll
          for (int nt = 0; nt < 4; ++nt)
#pragma unroll
            for (int kk = 0; kk < 2; ++kk)
              bfr[nt][kk] = *(const bf16x8*)&Bsl[(wc * 64 + nt * 16 + ml) * 64 +
                                                ((kk * 4 + quad) ^ (ml & 7)) * 8];
#pragma unroll
          for (int mt2 = 0; mt2 < 2; ++mt2)
#pragma unroll
            for (int kk = 0; kk < 2; ++kk)
              af[mt2][kk] = *(const bf16x8*)&Asl[(wr * 128 + mt2 * 16 + ml) * 64 +
                                                ((kk * 4 + quad) ^ (ml & 7)) * 8];
        } else {
          MEMFENCE; __builtin_amdgcn_s_barrier(); MEMFENCE;
        }
        __builtin_amdgcn_s_setprio(1);
#pragma unroll
        for (int mt2 = 0; mt2 < 2; ++mt2)
#pragma unroll
          for (int nt = 0; nt < 4; ++nt)
#pragma unroll
            for (int kk = 0; kk < 2; ++kk)
              acc[ph * 2 + mt2][nt] = __builtin_amdgcn_mfma_f32_16x16x32_bf16(
                  af[mt2][kk], bfr[nt][kk], acc[ph * 2 + mt2][nt], 0, 0, 0);
        __builtin_amdgcn_s_setprio(0);
        MEMFENCE; __builtin_amdgcn_s_barrier(); MEMFENCE;
      }
    }
  }
  // epilogue: bias (+gelu) + bf16 store; VSPLIT: V columns -> transposed vT
#pragma unroll
  for (int mt = 0; mt < 8; ++mt)
#pragma unroll
    for (int nt = 0; nt < 4; ++nt) {
      const int col0 = n0 + wc * 64 + nt * 16;
      const int row0 = m0 + wr * 128 + mt * 16;
      if (VSPLIT && col0 >= 2 * EMBED) {
        const int b = row0 >> 11, tok0 = row0 & (SEQ - 1);
        const int h = (col0 - 2 * EMBED) >> 6;
        const int dl = ((col0 - 2 * EMBED) & 63) + ml;
        float bia = bias[col0 + ml];
        ushort4 o;
        o.x = f2bf(acc[mt][nt][0] + bia);
        o.y = f2bf(acc[mt][nt][1] + bia);
        o.z = f2bf(acc[mt][nt][2] + bia);
        o.w = f2bf(acc[mt][nt][3] + bia);
        *(ushort4*)(vT + (size_t)((b * 16 + h) * 64 + dl) * SEQ + tok0 + quad * 4) = o;
      } else {
#pragma unroll
        for (int r = 0; r < 4; ++r) {
          int row = row0 + quad * 4 + r;
          int col = col0 + ml;
          float v = acc[mt][nt][r] + bias[col];
          if (ACT) v = fgelu(v);
          outB[(size_t)row * N + col] = f2bf(v);
        }
      }
    }
}

// ---------------- 128x64 NT GEMM, BK=64, XOR-swizzled LDS, XCD m-stripe grid.
// v3: 2-phase double-buffered prefetch (T3-min).
template <int RES, int OUTBF>
__global__ __launch_bounds__(256) void gemm64k(const unsigned short* __restrict__ A,
                                               const unsigned short* __restrict__ Wt,
                                               const float* __restrict__ bias,
                                               const float* __restrict__ res,
                                               unsigned short* __restrict__ outB,
                                               float* __restrict__ outF,
                                               int M, int N, int K, int nblk) {
  __shared__ __align__(16) unsigned short As[2][128 * 64];  // 32 KB
  __shared__ __align__(16) unsigned short Bs[2][64 * 64];   // 16 KB
  const int tid = threadIdx.x;
  const int wave = tid >> 6, lane = tid & 63;
  const int quad = lane >> 4, ml = lane & 15;
  const int wr = wave >> 1, wc = wave & 1;
  const int xcd = blockIdx.x & 7, idx = blockIdx.x >> 3;
  const int mPerXcd = (gridDim.x >> 3) / nblk;
  const int m0 = (xcd * mPerXcd + idx / nblk) * 128;
  const int n0 = (idx % nblk) * 64;
  const int srow = lane >> 3;
  const int schunk = (lane & 7) ^ (srow & 7);
  const unsigned short* Ag = A + (size_t)(m0 + wave * 32 + srow) * K + schunk * 8;
  const unsigned short* Bg = Wt + (size_t)(n0 + wave * 16 + srow) * K + schunk * 8;
  f32x4 acc[4][2];
#pragma unroll
  for (int i = 0; i < 4; i++) { acc[i][0] = (f32x4){0.f,0.f,0.f,0.f}; acc[i][1] = acc[i][0]; }
  {
    unsigned short* AsW = &As[0][wave * 2048];
    unsigned short* BsW = &Bs[0][wave * 1024];
    gload16(Ag, AsW);
    gload16(Ag + (size_t)8 * K,  AsW + 512);
    gload16(Ag + (size_t)16 * K, AsW + 1024);
    gload16(Ag + (size_t)24 * K, AsW + 1536);
    gload16(Bg, BsW);
    gload16(Bg + (size_t)8 * K,  BsW + 512);
    Ag += 64; Bg += 64;
  }
  __syncthreads();
  const int nk = K >> 6;
  for (int kk = 0; kk < nk; ++kk) {
    const int cur = kk & 1;
    if (kk + 1 < nk) {
      unsigned short* AsW = &As[cur ^ 1][wave * 2048];
      unsigned short* BsW = &Bs[cur ^ 1][wave * 1024];
      gload16(Ag, AsW);
      gload16(Ag + (size_t)8 * K,  AsW + 512);
      gload16(Ag + (size_t)16 * K, AsW + 1024);
      gload16(Ag + (size_t)24 * K, AsW + 1536);
      gload16(Bg, BsW);
      gload16(Bg + (size_t)8 * K,  BsW + 512);
      Ag += 64; Bg += 64;
    }
#pragma unroll
    for (int kh = 0; kh < 2; kh++) {
      const int ch = ((kh * 4 + quad) ^ (ml & 7)) * 8;
      bf16x8 af[4], bfr[2];
#pragma unroll
      for (int mt = 0; mt < 4; mt++)
        af[mt] = *(const bf16x8*)&As[cur][(wr * 64 + mt * 16 + ml) * 64 + ch];
#pragma unroll
      for (int nt = 0; nt < 2; nt++)
        bfr[nt] = *(const bf16x8*)&Bs[cur][(wc * 32 + nt * 16 + ml) * 64 + ch];
#pragma unroll
      for (int mt = 0; mt < 4; mt++)
#pragma unroll
        for (int nt = 0; nt < 2; nt++)
          acc[mt][nt] = __builtin_amdgcn_mfma_f32_16x16x32_bf16(af[mt], bfr[nt], acc[mt][nt], 0, 0, 0);
    }
    __syncthreads();
  }
#pragma unroll
  for (int mt = 0; mt < 4; mt++)
#pragma unroll
    for (int nt = 0; nt < 2; nt++)
#pragma unroll
      for (int r = 0; r < 4; r++) {
        int row = m0 + wr * 64 + mt * 16 + quad * 4 + r;
        int col = n0 + wc * 32 + nt * 16 + ml;
        float v = acc[mt][nt][r] + bias[col];
        if (RES) v += res[(size_t)row * N + col];
        if (OUTBF)
          outB[(size_t)row * N + col] = f2bf(v);
        else
          outF[(size_t)row * N + col] = v;
      }
}

// ---------------- flash attention v5: 32x32x16 MFMA + in-reg softmax + key-split waves.
// v5 fix: merge-scratch stride 48 -> 49 floats. Stride 48: bank = (lane*16+r)%32 -> all
// 64 lanes in 2 banks = 32-way conflict x 96 LDS ops/block (~2.9M of the 5.08M counted
// conflict cycles). Odd stride 49 -> lane*17%32 walks all residues -> <=2-way (free).
__global__ __launch_bounds__(256, 4) void attn_kernel(const unsigned short* __restrict__ qkv,
                                                      const unsigned short* __restrict__ vT,
                                                      unsigned short* __restrict__ attn) {
  __shared__ __align__(16) unsigned short Ks[2][64 * 64];  // 16 KB
  __shared__ __align__(16) unsigned short Vs[2][64 * 64];  // 16 KB
  const int tid = threadIdx.x, wave = tid >> 6, lane = tid & 63;
  const int l31 = lane & 31, hi = lane >> 5;
  const int qs = wave & 1, kh = wave >> 1;
  const int bh = blockIdx.x, b = bh >> 4, h = bh & 15;   // bh = fast grid axis
  const int q0w = blockIdx.y * 64 + qs * 32;
  const float qscale = 0.18033688011112042f;  // 0.125 * log2(e)
  const int sw = l31 & 7;

  const unsigned short* qrow = qkv + (size_t)(b * SEQ + q0w + l31) * QKV3 + h * HDIM;
  bf16x8 bq[4];
#pragma unroll
  for (int s = 0; s < 4; s++) {
    bq[s] = *(const bf16x8*)(qrow + s * 16 + hi * 8);
#pragma unroll
    for (int j = 0; j < 8; j++)
      bq[s][j] = (short)f2bf(bf2f((unsigned short)bq[s][j]) * qscale);
  }
  bf16x8 ones;
#pragma unroll
  for (int j = 0; j < 8; j++) ones[j] = (short)0x3F80;  // bf16 1.0

  f32x16 zz;
#pragma unroll
  for (int i = 0; i < 16; i++) zz[i] = 0.f;
  f32x16 O0 = zz, O1 = zz, lsum = zz;

  const int skey = lane >> 3;
  const int schunk8 = ((lane & 7) ^ (skey & 7)) * 8;
  const unsigned short* kbase =
      qkv + (size_t)(b * SEQ + wave * 16 + skey) * QKV3 + EMBED + h * HDIM + schunk8;
  const unsigned short* vbase =
      vT + (size_t)(bh * 64 + wave * 16 + skey) * SEQ + schunk8;

  gload16(kbase, &Ks[0][wave * 1024]);
  gload16(kbase + (size_t)8 * QKV3, &Ks[0][wave * 1024] + 512);
  gload16(vbase, &Vs[0][wave * 1024]);
  gload16(vbase + (size_t)8 * SEQ, &Vs[0][wave * 1024] + 512);
  __syncthreads();

  const int krow0 = kh * 32;
  for (int kti = 0; kti < SEQ / 64; ++kti) {
    const int cur = kti & 1;
    if (kti + 1 < SEQ / 64) {
      const int kt = (kti + 1) * 64;
      unsigned short* kd = &Ks[cur ^ 1][wave * 1024];
      unsigned short* vd = &Vs[cur ^ 1][wave * 1024];
      gload16(kbase + (size_t)kt * QKV3, kd);
      gload16(kbase + (size_t)(kt + 8) * QKV3, kd + 512);
      gload16(vbase + kt, vd);
      gload16(vbase + kt + (size_t)8 * SEQ, vd + 512);
    }
    const unsigned short* Kc = &Ks[cur][0];
    const unsigned short* Vc = &Vs[cur][0];

    f32x16 St = zz;
#pragma unroll
    for (int s = 0; s < 4; s++) {
      bf16x8 ak = *(const bf16x8*)&Kc[(krow0 + l31) * 64 + ((2 * s + hi) ^ sw) * 8];
      St = __builtin_amdgcn_mfma_f32_32x32x16_bf16(ak, bq[s], St, 0, 0, 0);
    }

    unsigned W0[4], W1[4];
#pragma unroll
    for (int g = 0; g < 4; g++) {
      W0[g] = pk2bf(fexp2(St[4 * g]), fexp2(St[4 * g + 1]));
      W1[g] = pk2bf(fexp2(St[4 * g + 2]), fexp2(St[4 * g + 3]));
    }

    bf16x8 pa[2];
#pragma unroll
    for (int ks = 0; ks < 2; ks++) {
      const int g0 = 2 * ks, g1 = g0 + 1;
      unsigned w0, w1, w2, w3;
      halfswap(W0[g0], W0[g1], hi, w0, w2);
      halfswap(W1[g0], W1[g1], hi, w1, w3);
      union { unsigned u[4]; bf16x8 v; } pw;
      pw.u[0] = w0; pw.u[1] = w1; pw.u[2] = w2; pw.u[3] = w3;
      pa[ks] = pw.v;
    }

    __builtin_amdgcn_s_setprio(1);
    lsum = __builtin_amdgcn_mfma_f32_32x32x16_bf16(pa[0], ones, lsum, 0, 0, 0);
    lsum = __builtin_amdgcn_mfma_f32_32x32x16_bf16(pa[1], ones, lsum, 0, 0, 0);
#pragma unroll
    for (int ks = 0; ks < 2; ks++) {
      const int ch = kh * 4 + ks * 2 + hi;
      bf16x8 bv0 = *(const bf16x8*)&Vc[l31 * 64 + (ch ^ sw) * 8];
      bf16x8 bv1 = *(const bf16x8*)&Vc[(32 + l31) * 64 + (ch ^ sw) * 8];
      O0 = __builtin_amdgcn_mfma_f32_32x32x16_bf16(pa[ks], bv0, O0, 0, 0, 0);
      O1 = __builtin_amdgcn_mfma_f32_32x32x16_bf16(pa[ks], bv1, O1, 0, 0, 0);
    }
    __builtin_amdgcn_s_setprio(0);
    __syncthreads();
  }

  // merge key-half partials via LDS (stride 49 floats: conflict-free; 63*49+47 < 4096)
  if (kh == 1) {
    float* sc = qs ? (float*)&Vs[0][0] : (float*)&Ks[0][0];
#pragma unroll
    for (int r = 0; r < 16; r++) {
      sc[lane * 49 + r]      = lsum[r];
      sc[lane * 49 + 16 + r] = O0[r];
      sc[lane * 49 + 32 + r] = O1[r];
    }
  }
  __syncthreads();
  if (kh == 0) {
    const float* sc = qs ? (const float*)&Vs[0][0] : (const float*)&Ks[0][0];
#pragma unroll
    for (int r = 0; r < 16; r++) {
      lsum[r] += sc[lane * 49 + r];
      O0[r]   += sc[lane * 49 + 16 + r];
      O1[r]   += sc[lane * 49 + 32 + r];
    }
#pragma unroll
    for (int r = 0; r < 16; r++) {
      const int qr = (r & 3) + 8 * (r >> 2) + 4 * hi;
      float inv = 1.0f / lsum[r];
      size_t g = (size_t)(b * SEQ + q0w + qr) * EMBED + h * HDIM + l31;
      attn[g]      = f2bf(O0[r] * inv);
      attn[g + 32] = f2bf(O1[r] * inv);
    }
  }
}

extern "C" void kernel_launch(void* const* d_in, const int* in_sizes, int n_in,
                              void* d_out, int out_size, void* d_ws, size_t ws_size,
                              hipStream_t stream) {
  const float* x      = (const float*)d_in[0];
  const float* ln1_w  = (const float*)d_in[1];
  const float* ln1_b  = (const float*)d_in[2];
  const float* ln2_w  = (const float*)d_in[3];
  const float* ln2_b  = (const float*)d_in[4];
  const float* qkv_w  = (const float*)d_in[5];
  const float* qkv_b  = (const float*)d_in[6];
  const float* proj_w = (const float*)d_in[7];
  const float* proj_b = (const float*)d_in[8];
  const float* fc1_w  = (const float*)d_in[9];
  const float* fc1_b  = (const float*)d_in[10];
  const float* fc2_w  = (const float*)d_in[11];
  const float* fc2_b  = (const float*)d_in[12];
  float* out = (float*)d_out;
  char* wsb = (char*)d_ws;
  unsigned short* lnbuf  = (unsigned short*)(wsb + 0);
  unsigned short* qkvb   = (unsigned short*)(wsb + 8388608);
  unsigned short* attnb  = (unsigned short*)(wsb + 33554432);
  unsigned short* vTb    = (unsigned short*)(wsb + 41943040);
  unsigned short* actb   = (unsigned short*)(wsb + 33554432);
  float*          h1     = (float*)(wsb + 67108864);
  unsigned short* qkvWt  = (unsigned short*)(wsb + 83886080);
  unsigned short* projWt = (unsigned short*)(wsb + 90177536);
  unsigned short* fc1Wt  = (unsigned short*)(wsb + 92274688);
  unsigned short* fc2Wt  = (unsigned short*)(wsb + 100663296);

  TD4 td;
  td.d[0] = {qkv_w,  qkvWt,  1024, 3072,  96, 0};
  td.d[1] = {proj_w, projWt, 1024, 1024,  32, 3072};
  td.d[2] = {fc1_w,  fc1Wt,  1024, 4096, 128, 4096};
  td.d[3] = {fc2_w,  fc2Wt,  4096, 1024,  32, 8192};
  transpose_all<<<12288, dim3(32, 8), 0, stream>>>(td);

  ln_kernel<<<MTOK, 256, 0, stream>>>(x, ln1_w, ln1_b, lnbuf);
  gemmBig<0, 1, 1><<<768, 256, 0, stream>>>(
      lnbuf, qkvWt, qkv_b, qkvb, nullptr, vTb, MTOK, QKV3, EMBED, 24);
  attn_kernel<<<dim3(32, 32), 256, 0, stream>>>(qkvb, vTb, attnb);
  gemm64k<1, 0><<<512, 256, 0, stream>>>(
      attnb, projWt, proj_b, x, nullptr, h1, MTOK, EMBED, EMBED, 16);
  ln_kernel<<<MTOK, 256, 0, stream>>>(h1, ln2_w, ln2_b, lnbuf);
  gemm256<1, 0><<<256, 512, 0, stream>>>(
      lnbuf, fc1Wt, fc1_b, actb, nullptr, MTOK, FFN, EMBED, 16);
  gemm64k<1, 0><<<512, 256, 0, stream>>>(
      actb, fc2Wt, fc2_b, h1, nullptr, out, MTOK, EMBED, FFN, 16);
}

// Round 9
// 337.547 us; speedup vs baseline: 1.0206x; 1.0145x over previous
//
#include <hip/hip_runtime.h>
#include <hip/hip_bf16.h>

#define SEQ    2048
#define BATCH  2
#define MTOK   4096
#define EMBED  1024
#define HEADS  16
#define HDIM   64
#define QKV3   3072
#define FFN    4096

typedef __attribute__((ext_vector_type(8))) short bf16x8;
typedef __attribute__((ext_vector_type(4))) float f32x4;
typedef __attribute__((ext_vector_type(16))) float f32x16;

static __device__ __forceinline__ unsigned short f2bf(float f) {
  union { float f; unsigned u; } x; x.f = f;
  unsigned r = x.u + 0x7FFFu + ((x.u >> 16) & 1u);
  return (unsigned short)(r >> 16);
}
static __device__ __forceinline__ float bf2f(unsigned short u) {
  union { unsigned u; float f; } x; x.u = ((unsigned)u) << 16; return x.f;
}
static __device__ __forceinline__ unsigned pk2bf(float a, float b) {
#if __has_builtin(__builtin_amdgcn_cvt_pk_bf16_f32)
  typedef __attribute__((ext_vector_type(2))) __bf16 bf16x2_t;
  union { bf16x2_t v; unsigned u; } x;
  x.v = __builtin_amdgcn_cvt_pk_bf16_f32(a, b);
  return x.u;
#else
  return ((unsigned)f2bf(a)) | (((unsigned)f2bf(b)) << 16);
#endif
}
static __device__ __forceinline__ float fexp2(float x) {
#if __has_builtin(__builtin_amdgcn_exp2f)
  return __builtin_amdgcn_exp2f(x);
#else
  return exp2f(x);
#endif
}
static __device__ __forceinline__ float frcp(float x) {
#if __has_builtin(__builtin_amdgcn_rcpf)
  return __builtin_amdgcn_rcpf(x);
#else
  return 1.0f / x;
#endif
}
// gelu(v) = v * sigmoid(1.5957691*(v + 0.044715 v^3)); sigmoid via exp2.
static __device__ __forceinline__ float fgelu(float v) {
  float t = v * v;
  float z = v * __builtin_fmaf(-0.1029456f, t, -2.3022650687f);
  return v * frcp(1.0f + fexp2(z));
}

// half-swap across the lane<32 / lane>=32 split:
//   lo_out = concat(a[0:32], b[0:32])   hi_out = concat(a[32:64], b[32:64])
static __device__ __forceinline__ void halfswap(unsigned a, unsigned b, int hi,
                                                unsigned& lo_out, unsigned& hi_out) {
#if __has_builtin(__builtin_amdgcn_permlane32_swap)
  typedef __attribute__((ext_vector_type(2))) unsigned uint2v;
  uint2v r = __builtin_amdgcn_permlane32_swap(a, b, false, false);
  lo_out = r[0];
  hi_out = r[1];
#else
  unsigned as = (unsigned)__shfl_xor((int)a, 32);
  unsigned bs = (unsigned)__shfl_xor((int)b, 32);
  lo_out = hi ? bs : a;
  hi_out = hi ? b : as;
#endif
}

// async global->LDS, 16B per lane; lds dest is wave-uniform base + lane*16
static __device__ __forceinline__ void gload16(const unsigned short* g, unsigned short* l) {
  __builtin_amdgcn_global_load_lds((const __attribute__((address_space(1))) void*)g,
                                   (__attribute__((address_space(3))) void*)l, 16, 0, 0);
}

#define MEMFENCE asm volatile("" ::: "memory")

// ---------------- fused weight transpose + fp32->bf16: Wt[n][k] = W[k][n] (all 4 weights)
struct TD { const float* W; unsigned short* T; int K, N, ntx, base; };
struct TD4 { TD d[4]; };

__global__ void transpose_all(TD4 td) {
  __shared__ float t[32][33];
  int bid = blockIdx.x;
  int i = 0;
  if (bid >= td.d[1].base) i = 1;
  if (bid >= td.d[2].base) i = 2;
  if (bid >= td.d[3].base) i = 3;
  const TD& D = td.d[i];
  int local = bid - D.base;
  int n0 = (local % D.ntx) * 32, k0 = (local / D.ntx) * 32;
  int tx = threadIdx.x, ty = threadIdx.y;  // block (32,8)
#pragma unroll
  for (int j = 0; j < 32; j += 8)
    t[ty + j][tx] = D.W[(size_t)(k0 + ty + j) * D.N + n0 + tx];
  __syncthreads();
#pragma unroll
  for (int j = 0; j < 32; j += 8)
    D.T[(size_t)(n0 + ty + j) * D.K + k0 + tx] = f2bf(t[tx][ty + j]);
}

// ---------------- layernorm (one token per block), fp32 in -> bf16 out
__global__ __launch_bounds__(256) void ln_kernel(const float* __restrict__ in,
                                                 const float* __restrict__ w,
                                                 const float* __restrict__ b,
                                                 unsigned short* __restrict__ out) {
  __shared__ float sh[4];
  int row = blockIdx.x, tid = threadIdx.x;
  const float4 v = ((const float4*)(in + (size_t)row * EMBED))[tid];
  float s = v.x + v.y + v.z + v.w;
#pragma unroll
  for (int off = 32; off; off >>= 1) s += __shfl_xor(s, off);
  if ((tid & 63) == 0) sh[tid >> 6] = s;
  __syncthreads();
  float mean = (sh[0] + sh[1] + sh[2] + sh[3]) * (1.0f / EMBED);
  __syncthreads();
  float dx = v.x - mean, dy = v.y - mean, dz = v.z - mean, dw = v.w - mean;
  float q = dx * dx + dy * dy + dz * dz + dw * dw;
#pragma unroll
  for (int off = 32; off; off >>= 1) q += __shfl_xor(q, off);
  if ((tid & 63) == 0) sh[tid >> 6] = q;
  __syncthreads();
  float var = (sh[0] + sh[1] + sh[2] + sh[3]) * (1.0f / EMBED);
  float rs = rsqrtf(var + 1e-5f);
  const float4 wv = ((const float4*)w)[tid];
  const float4 bv = ((const float4*)b)[tid];
  ushort4 o;
  o.x = f2bf(dx * rs * wv.x + bv.x);
  o.y = f2bf(dy * rs * wv.y + bv.y);
  o.z = f2bf(dz * rs * wv.z + bv.z);
  o.w = f2bf(dw * rs * wv.w + bv.w);
  ((ushort4*)(out + (size_t)row * EMBED))[tid] = o;
}

// ---------------- 128x128 NT bf16 GEMM, BK=64, XOR-swizzled LDS (128B rows),
// plain n-fastest block order (QKV engine — proven config).
template <int ACT, int OUTBF, int VSPLIT>
__global__ __launch_bounds__(256) void gemmBig(const unsigned short* __restrict__ A,
                                               const unsigned short* __restrict__ Wt,
                                               const float* __restrict__ bias,
                                               unsigned short* __restrict__ outB,
                                               float* __restrict__ outF,
                                               unsigned short* __restrict__ vT,
                                               int M, int N, int K, int nblk) {
  __shared__ __align__(16) unsigned short As[128 * 64];  // 16 KB
  __shared__ __align__(16) unsigned short Bs[128 * 64];  // 16 KB
  const int tid = threadIdx.x;
  const int wave = tid >> 6, lane = tid & 63;
  const int quad = lane >> 4, ml = lane & 15;
  const int wr = wave >> 1, wc = wave & 1;
  const int m0 = (blockIdx.x / nblk) * 128;
  const int n0 = (blockIdx.x % nblk) * 128;
  const int srow = lane >> 3;
  const int schunk = (lane & 7) ^ (srow & 7);
  const unsigned short* Ag = A + (size_t)(m0 + wave * 32 + srow) * K + schunk * 8;
  const unsigned short* Bg = Wt + (size_t)(n0 + wave * 32 + srow) * K + schunk * 8;
  unsigned short* AsW = &As[wave * 2048];
  unsigned short* BsW = &Bs[wave * 2048];
  f32x4 acc[4][4];
#pragma unroll
  for (int i = 0; i < 4; i++)
#pragma unroll
    for (int j = 0; j < 4; j++) acc[i][j] = (f32x4){0.f, 0.f, 0.f, 0.f};
  for (int k0 = 0; k0 < K; k0 += 64) {
    __syncthreads();
#pragma unroll
    for (int t = 0; t < 4; t++) {
      gload16(Ag + (size_t)(8 * t) * K, AsW + 512 * t);
      gload16(Bg + (size_t)(8 * t) * K, BsW + 512 * t);
    }
    Ag += 64; Bg += 64;
    __syncthreads();
#pragma unroll
    for (int kh = 0; kh < 2; kh++) {
      const int ch = ((kh * 4 + quad) ^ (ml & 7)) * 8;
      bf16x8 af[4], bfr[4];
#pragma unroll
      for (int mt = 0; mt < 4; mt++)
        af[mt] = *(const bf16x8*)&As[(wr * 64 + mt * 16 + ml) * 64 + ch];
#pragma unroll
      for (int nt = 0; nt < 4; nt++)
        bfr[nt] = *(const bf16x8*)&Bs[(wc * 64 + nt * 16 + ml) * 64 + ch];
#pragma unroll
      for (int mt = 0; mt < 4; mt++)
#pragma unroll
        for (int nt = 0; nt < 4; nt++)
          acc[mt][nt] = __builtin_amdgcn_mfma_f32_16x16x32_bf16(af[mt], bfr[nt], acc[mt][nt], 0, 0, 0);
    }
  }
#pragma unroll
  for (int mt = 0; mt < 4; mt++)
#pragma unroll
    for (int nt = 0; nt < 4; nt++) {
      const int col0 = n0 + wc * 64 + nt * 16;
      const int row0 = m0 + wr * 64 + mt * 16;
      if (VSPLIT && col0 >= 2 * EMBED) {
        const int b = row0 >> 11, tok0 = row0 & (SEQ - 1);
        const int h = (col0 - 2 * EMBED) >> 6;
        const int dl = ((col0 - 2 * EMBED) & 63) + ml;
        float bia = bias[col0 + ml];
        ushort4 o;
        o.x = f2bf(acc[mt][nt][0] + bia);
        o.y = f2bf(acc[mt][nt][1] + bia);
        o.z = f2bf(acc[mt][nt][2] + bia);
        o.w = f2bf(acc[mt][nt][3] + bia);
        *(ushort4*)(vT + (size_t)((b * 16 + h) * 64 + dl) * SEQ + tok0 + quad * 4) = o;
      } else {
#pragma unroll
        for (int r = 0; r < 4; r++) {
          int row = row0 + quad * 4 + r;
          int col = col0 + ml;
          float v = acc[mt][nt][r] + bias[col];
          if (ACT) v = fgelu(v);
          if (OUTBF)
            outB[(size_t)row * N + col] = f2bf(v);
          else
            outF[(size_t)row * N + col] = v;
        }
      }
    }
}

// ---------------- 256x256 8-phase GEMM (T3+T4+T2+T5), BK=64, dual K-tile slots.
// (FC1 engine — exact-CU-fill 256 blocks; proven in round 6.)
template <int ACT, int VSPLIT>
__global__ __launch_bounds__(512, 2) void gemm256(const unsigned short* __restrict__ A,
                                                  const unsigned short* __restrict__ Wt,
                                                  const float* __restrict__ bias,
                                                  unsigned short* __restrict__ outB,
                                                  unsigned short* __restrict__ vT,
                                                  int M, int N, int K, int nblk) {
  __shared__ __align__(16) unsigned short As[2][256 * 64];  // 64 KB
  __shared__ __align__(16) unsigned short Bs[2][256 * 64];  // 64 KB
  const int tid = threadIdx.x;
  const int wave = tid >> 6, lane = tid & 63;
  const int quad = lane >> 4, ml = lane & 15;
  const int wr = wave >> 2, wc = wave & 3;  // 2M x 4N wave grid
  const int m0 = (blockIdx.x / nblk) * 256;
  const int n0 = (blockIdx.x % nblk) * 256;
  const int srow = lane >> 3;
  const int schunk = (lane & 7) ^ (srow & 7);
  const unsigned short* Ag = A  + (size_t)(m0 + wave * 32 + srow) * K + schunk * 8;
  const unsigned short* Bg = Wt + (size_t)(n0 + wave * 32 + srow) * K + schunk * 8;
  f32x4 acc[8][4];
#pragma unroll
  for (int i = 0; i < 8; i++)
#pragma unroll
    for (int j = 0; j < 4; j++) acc[i][j] = (f32x4){0.f, 0.f, 0.f, 0.f};

  // prologue: stage K-tile 0 -> slot 0 (8 gload16/wave)
#pragma unroll
  for (int g = 0; g < 4; g++) {
    gload16(Ag + (size_t)(g * 8) * K, &As[0][(wave * 32 + g * 8) * 64]);
    gload16(Bg + (size_t)(g * 8) * K, &Bs[0][(wave * 32 + g * 8) * 64]);
  }

  const int nit = K >> 7;  // 2 K-tiles per iteration
  for (int it = 0; it < nit; ++it) {
#pragma unroll
    for (int half = 0; half < 2; ++half) {
      const int rs = half;                 // slot being read this half
      const int ss = half ^ 1;             // slot being staged this half
      const int kst = 2 * it + 1 + half;   // K-tile being staged
      const bool doStage = (kst < 2 * nit);
      const unsigned short* Asl = &As[rs][0];
      const unsigned short* Bsl = &Bs[rs][0];
      bf16x8 bfr[4][2];
#pragma unroll
      for (int ph = 0; ph < 4; ++ph) {
        bf16x8 af[2][2];
        if (ph > 0) {
#pragma unroll
          for (int mt2 = 0; mt2 < 2; ++mt2)
#pragma unroll
            for (int kk = 0; kk < 2; ++kk)
              af[mt2][kk] = *(const bf16x8*)&Asl[(wr * 128 + (ph * 2 + mt2) * 16 + ml) * 64 +
                                                ((kk * 4 + quad) ^ (ml & 7)) * 8];
        }
        if (doStage) {
          if (ph < 2) {
            gload16(Ag + (size_t)((ph * 2) * 8) * K + kst * 64,
                    &As[ss][(wave * 32 + (ph * 2) * 8) * 64]);
            gload16(Ag + (size_t)((ph * 2 + 1) * 8) * K + kst * 64,
                    &As[ss][(wave * 32 + (ph * 2 + 1) * 8) * 64]);
          } else {
            gload16(Bg + (size_t)(((ph - 2) * 2) * 8) * K + kst * 64,
                    &Bs[ss][(wave * 32 + ((ph - 2) * 2) * 8) * 64]);
            gload16(Bg + (size_t)(((ph - 2) * 2 + 1) * 8) * K + kst * 64,
                    &Bs[ss][(wave * 32 + ((ph - 2) * 2 + 1) * 8) * 64]);
          }
        }
        if (ph == 0) {
          if (doStage) { asm volatile("s_waitcnt vmcnt(2)" ::: "memory"); }
          else         { asm volatile("s_waitcnt vmcnt(0)" ::: "memory"); }
          MEMFENCE; __builtin_amdgcn_s_barrier(); MEMFENCE;
#pragma unroll
          for (int nt = 0; nt < 4; ++nt)
#pragma unroll
            for (int kk = 0; kk < 2; ++kk)
              bfr[nt][kk] = *(const bf16x8*)&Bsl[(wc * 64 + nt * 16 + ml) * 64 +
                                                ((kk * 4 + quad) ^ (ml & 7)) * 8];
#pragma unroll
          for (int mt2 = 0; mt2 < 2; ++mt2)
#pragma unroll
            for (int kk = 0; kk < 2; ++kk)
              af[mt2][kk] = *(const bf16x8*)&Asl[(wr * 128 + mt2 * 16 + ml) * 64 +
                                                ((kk * 4 + quad) ^ (ml & 7)) * 8];
        } else {
          MEMFENCE; __builtin_amdgcn_s_barrier(); MEMFENCE;
        }
        __builtin_amdgcn_s_setprio(1);
#pragma unroll
        for (int mt2 = 0; mt2 < 2; ++mt2)
#pragma unroll
          for (int nt = 0; nt < 4; ++nt)
#pragma unroll
            for (int kk = 0; kk < 2; ++kk)
              acc[ph * 2 + mt2][nt] = __builtin_amdgcn_mfma_f32_16x16x32_bf16(
                  af[mt2][kk], bfr[nt][kk], acc[ph * 2 + mt2][nt], 0, 0, 0);
        __builtin_amdgcn_s_setprio(0);
        MEMFENCE; __builtin_amdgcn_s_barrier(); MEMFENCE;
      }
    }
  }
#pragma unroll
  for (int mt = 0; mt < 8; ++mt)
#pragma unroll
    for (int nt = 0; nt < 4; ++nt) {
      const int col0 = n0 + wc * 64 + nt * 16;
      const int row0 = m0 + wr * 128 + mt * 16;
      if (VSPLIT && col0 >= 2 * EMBED) {
        const int b = row0 >> 11, tok0 = row0 & (SEQ - 1);
        const int h = (col0 - 2 * EMBED) >> 6;
        const int dl = ((col0 - 2 * EMBED) & 63) + ml;
        float bia = bias[col0 + ml];
        ushort4 o;
        o.x = f2bf(acc[mt][nt][0] + bia);
        o.y = f2bf(acc[mt][nt][1] + bia);
        o.z = f2bf(acc[mt][nt][2] + bia);
        o.w = f2bf(acc[mt][nt][3] + bia);
        *(ushort4*)(vT + (size_t)((b * 16 + h) * 64 + dl) * SEQ + tok0 + quad * 4) = o;
      } else {
#pragma unroll
        for (int r = 0; r < 4; ++r) {
          int row = row0 + quad * 4 + r;
          int col = col0 + ml;
          float v = acc[mt][nt][r] + bias[col];
          if (ACT) v = fgelu(v);
          outB[(size_t)row * N + col] = f2bf(v);
        }
      }
    }
}

// ---------------- 128x64 NT GEMM v4: triple-slot LDS + COUNTED vmcnt (T4), never drain.
// Grid 512 = 2 blocks/CU. 6 gload16/tile/wave; 2 tiles in flight.
// Iter k: issue stage(k+2) -> vmcnt(12) (own 12 newest = tiles k+1,k+2; tile k's 6 are
// older -> landed) -> s_barrier -> compute slot k%3 -> s_barrier (orders slot reads vs
// iter k+1's stage into slot (k+3)%3 == k%3). Tail: vmcnt(6) then vmcnt(0).
// LDS 3x(16+8) = 72 KB -> 2 blocks/CU (144 KB).
template <int RES, int OUTBF>
__global__ __launch_bounds__(256) void gemm64k(const unsigned short* __restrict__ A,
                                               const unsigned short* __restrict__ Wt,
                                               const float* __restrict__ bias,
                                               const float* __restrict__ res,
                                               unsigned short* __restrict__ outB,
                                               float* __restrict__ outF,
                                               int M, int N, int K, int nblk) {
  __shared__ __align__(16) unsigned short As[3][128 * 64];  // 48 KB
  __shared__ __align__(16) unsigned short Bs[3][64 * 64];   // 24 KB
  const int tid = threadIdx.x;
  const int wave = tid >> 6, lane = tid & 63;
  const int quad = lane >> 4, ml = lane & 15;
  const int wr = wave >> 1, wc = wave & 1;
  const int xcd = blockIdx.x & 7, idx = blockIdx.x >> 3;
  const int mPerXcd = (gridDim.x >> 3) / nblk;
  const int m0 = (xcd * mPerXcd + idx / nblk) * 128;
  const int n0 = (idx % nblk) * 64;
  const int srow = lane >> 3;
  const int schunk = (lane & 7) ^ (srow & 7);
  const unsigned short* Ag = A + (size_t)(m0 + wave * 32 + srow) * K + schunk * 8;
  const unsigned short* Bg = Wt + (size_t)(n0 + wave * 16 + srow) * K + schunk * 8;
  f32x4 acc[4][2];
#pragma unroll
  for (int i = 0; i < 4; i++) { acc[i][0] = (f32x4){0.f,0.f,0.f,0.f}; acc[i][1] = acc[i][0]; }

  // prologue: stage tiles 0 and 1 into slots 0 and 1 (6 loads each)
#pragma unroll
  for (int p = 0; p < 2; ++p) {
    unsigned short* AsW = &As[p][wave * 2048];
    unsigned short* BsW = &Bs[p][wave * 1024];
    gload16(Ag, AsW);
    gload16(Ag + (size_t)8 * K,  AsW + 512);
    gload16(Ag + (size_t)16 * K, AsW + 1024);
    gload16(Ag + (size_t)24 * K, AsW + 1536);
    gload16(Bg, BsW);
    gload16(Bg + (size_t)8 * K,  BsW + 512);
    Ag += 64; Bg += 64;
  }

  const int nk = K >> 6;
  int ss = 2;  // staging slot for tile kk+2
  for (int kk = 0; kk < nk; ++kk) {
    if (kk + 2 < nk) {
      unsigned short* AsW = &As[ss][wave * 2048];
      unsigned short* BsW = &Bs[ss][wave * 1024];
      gload16(Ag, AsW);
      gload16(Ag + (size_t)8 * K,  AsW + 512);
      gload16(Ag + (size_t)16 * K, AsW + 1024);
      gload16(Ag + (size_t)24 * K, AsW + 1536);
      gload16(Bg, BsW);
      gload16(Bg + (size_t)8 * K,  BsW + 512);
      Ag += 64; Bg += 64;
      asm volatile("s_waitcnt vmcnt(12)" ::: "memory");  // tile kk landed
    } else if (kk + 1 < nk) {
      asm volatile("s_waitcnt vmcnt(6)" ::: "memory");   // tile kk landed
    } else {
      asm volatile("s_waitcnt vmcnt(0)" ::: "memory");
    }
    MEMFENCE; __builtin_amdgcn_s_barrier(); MEMFENCE;    // all waves' tile-kk loads done
    const int cs = kk - 3 * ((kk * 0x5556) >> 16);       // kk % 3 (kk < 21846)
    const unsigned short* Asl = &As[cs][0];
    const unsigned short* Bsl = &Bs[cs][0];
#pragma unroll
    for (int kh = 0; kh < 2; kh++) {
      const int ch = ((kh * 4 + quad) ^ (ml & 7)) * 8;
      bf16x8 af[4], bfr[2];
#pragma unroll
      for (int mt = 0; mt < 4; mt++)
        af[mt] = *(const bf16x8*)&Asl[(wr * 64 + mt * 16 + ml) * 64 + ch];
#pragma unroll
      for (int nt = 0; nt < 2; nt++)
        bfr[nt] = *(const bf16x8*)&Bsl[(wc * 32 + nt * 16 + ml) * 64 + ch];
#pragma unroll
      for (int mt = 0; mt < 4; mt++)
#pragma unroll
        for (int nt = 0; nt < 2; nt++)
          acc[mt][nt] = __builtin_amdgcn_mfma_f32_16x16x32_bf16(af[mt], bfr[nt], acc[mt][nt], 0, 0, 0);
    }
    // protect slot cs: iter kk+1 stages tile kk+3 into slot (kk+3)%3 == cs
    MEMFENCE; __builtin_amdgcn_s_barrier(); MEMFENCE;
    ss = (ss == 2) ? 0 : ss + 1;
  }
#pragma unroll
  for (int mt = 0; mt < 4; mt++)
#pragma unroll
    for (int nt = 0; nt < 2; nt++)
#pragma unroll
      for (int r = 0; r < 4; r++) {
        int row = m0 + wr * 64 + mt * 16 + quad * 4 + r;
        int col = n0 + wc * 32 + nt * 16 + ml;
        float v = acc[mt][nt][r] + bias[col];
        if (RES) v += res[(size_t)row * N + col];
        if (OUTBF)
          outB[(size_t)row * N + col] = f2bf(v);
        else
          outF[(size_t)row * N + col] = v;
      }
}

// ---------------- flash attention v5: 32x32x16 MFMA + in-reg softmax + key-split waves.
__global__ __launch_bounds__(256, 4) void attn_kernel(const unsigned short* __restrict__ qkv,
                                                      const unsigned short* __restrict__ vT,
                                                      unsigned short* __restrict__ attn) {
  __shared__ __align__(16) unsigned short Ks[2][64 * 64];  // 16 KB
  __shared__ __align__(16) unsigned short Vs[2][64 * 64];  // 16 KB
  const int tid = threadIdx.x, wave = tid >> 6, lane = tid & 63;
  const int l31 = lane & 31, hi = lane >> 5;
  const int qs = wave & 1, kh = wave >> 1;
  const int bh = blockIdx.x, b = bh >> 4, h = bh & 15;   // bh = fast grid axis
  const int q0w = blockIdx.y * 64 + qs * 32;
  const float qscale = 0.18033688011112042f;  // 0.125 * log2(e)
  const int sw = l31 & 7;

  const unsigned short* qrow = qkv + (size_t)(b * SEQ + q0w + l31) * QKV3 + h * HDIM;
  bf16x8 bq[4];
#pragma unroll
  for (int s = 0; s < 4; s++) {
    bq[s] = *(const bf16x8*)(qrow + s * 16 + hi * 8);
#pragma unroll
    for (int j = 0; j < 8; j++)
      bq[s][j] = (short)f2bf(bf2f((unsigned short)bq[s][j]) * qscale);
  }
  bf16x8 ones;
#pragma unroll
  for (int j = 0; j < 8; j++) ones[j] = (short)0x3F80;  // bf16 1.0

  f32x16 zz;
#pragma unroll
  for (int i = 0; i < 16; i++) zz[i] = 0.f;
  f32x16 O0 = zz, O1 = zz, lsum = zz;

  const int skey = lane >> 3;
  const int schunk8 = ((lane & 7) ^ (skey & 7)) * 8;
  const unsigned short* kbase =
      qkv + (size_t)(b * SEQ + wave * 16 + skey) * QKV3 + EMBED + h * HDIM + schunk8;
  const unsigned short* vbase =
      vT + (size_t)(bh * 64 + wave * 16 + skey) * SEQ + schunk8;

  gload16(kbase, &Ks[0][wave * 1024]);
  gload16(kbase + (size_t)8 * QKV3, &Ks[0][wave * 1024] + 512);
  gload16(vbase, &Vs[0][wave * 1024]);
  gload16(vbase + (size_t)8 * SEQ, &Vs[0][wave * 1024] + 512);
  __syncthreads();

  const int krow0 = kh * 32;
  for (int kti = 0; kti < SEQ / 64; ++kti) {
    const int cur = kti & 1;
    if (kti + 1 < SEQ / 64) {
      const int kt = (kti + 1) * 64;
      unsigned short* kd = &Ks[cur ^ 1][wave * 1024];
      unsigned short* vd = &Vs[cur ^ 1][wave * 1024];
      gload16(kbase + (size_t)kt * QKV3, kd);
      gload16(kbase + (size_t)(kt + 8) * QKV3, kd + 512);
      gload16(vbase + kt, vd);
      gload16(vbase + kt + (size_t)8 * SEQ, vd + 512);
    }
    const unsigned short* Kc = &Ks[cur][0];
    const unsigned short* Vc = &Vs[cur][0];

    f32x16 St = zz;
#pragma unroll
    for (int s = 0; s < 4; s++) {
      bf16x8 ak = *(const bf16x8*)&Kc[(krow0 + l31) * 64 + ((2 * s + hi) ^ sw) * 8];
      St = __builtin_amdgcn_mfma_f32_32x32x16_bf16(ak, bq[s], St, 0, 0, 0);
    }

    unsigned W0[4], W1[4];
#pragma unroll
    for (int g = 0; g < 4; g++) {
      W0[g] = pk2bf(fexp2(St[4 * g]), fexp2(St[4 * g + 1]));
      W1[g] = pk2bf(fexp2(St[4 * g + 2]), fexp2(St[4 * g + 3]));
    }

    bf16x8 pa[2];
#pragma unroll
    for (int ks = 0; ks < 2; ks++) {
      const int g0 = 2 * ks, g1 = g0 + 1;
      unsigned w0, w1, w2, w3;
      halfswap(W0[g0], W0[g1], hi, w0, w2);
      halfswap(W1[g0], W1[g1], hi, w1, w3);
      union { unsigned u[4]; bf16x8 v; } pw;
      pw.u[0] = w0; pw.u[1] = w1; pw.u[2] = w2; pw.u[3] = w3;
      pa[ks] = pw.v;
    }

    __builtin_amdgcn_s_setprio(1);
    lsum = __builtin_amdgcn_mfma_f32_32x32x16_bf16(pa[0], ones, lsum, 0, 0, 0);
    lsum = __builtin_amdgcn_mfma_f32_32x32x16_bf16(pa[1], ones, lsum, 0, 0, 0);
#pragma unroll
    for (int ks = 0; ks < 2; ks++) {
      const int ch = kh * 4 + ks * 2 + hi;
      bf16x8 bv0 = *(const bf16x8*)&Vc[l31 * 64 + (ch ^ sw) * 8];
      bf16x8 bv1 = *(const bf16x8*)&Vc[(32 + l31) * 64 + (ch ^ sw) * 8];
      O0 = __builtin_amdgcn_mfma_f32_32x32x16_bf16(pa[ks], bv0, O0, 0, 0, 0);
      O1 = __builtin_amdgcn_mfma_f32_32x32x16_bf16(pa[ks], bv1, O1, 0, 0, 0);
    }
    __builtin_amdgcn_s_setprio(0);
    __syncthreads();
  }

  // merge key-half partials via LDS (stride 49 floats: conflict-free; 63*49+47 < 4096)
  if (kh == 1) {
    float* sc = qs ? (float*)&Vs[0][0] : (float*)&Ks[0][0];
#pragma unroll
    for (int r = 0; r < 16; r++) {
      sc[lane * 49 + r]      = lsum[r];
      sc[lane * 49 + 16 + r] = O0[r];
      sc[lane * 49 + 32 + r] = O1[r];
    }
  }
  __syncthreads();
  if (kh == 0) {
    const float* sc = qs ? (const float*)&Vs[0][0] : (const float*)&Ks[0][0];
#pragma unroll
    for (int r = 0; r < 16; r++) {
      lsum[r] += sc[lane * 49 + r];
      O0[r]   += sc[lane * 49 + 16 + r];
      O1[r]   += sc[lane * 49 + 32 + r];
    }
#pragma unroll
    for (int r = 0; r < 16; r++) {
      const int qr = (r & 3) + 8 * (r >> 2) + 4 * hi;
      float inv = 1.0f / lsum[r];
      size_t g = (size_t)(b * SEQ + q0w + qr) * EMBED + h * HDIM + l31;
      attn[g]      = f2bf(O0[r] * inv);
      attn[g + 32] = f2bf(O1[r] * inv);
    }
  }
}

extern "C" void kernel_launch(void* const* d_in, const int* in_sizes, int n_in,
                              void* d_out, int out_size, void* d_ws, size_t ws_size,
                              hipStream_t stream) {
  const float* x      = (const float*)d_in[0];
  const float* ln1_w  = (const float*)d_in[1];
  const float* ln1_b  = (const float*)d_in[2];
  const float* ln2_w  = (const float*)d_in[3];
  const float* ln2_b  = (const float*)d_in[4];
  const float* qkv_w  = (const float*)d_in[5];
  const float* qkv_b  = (const float*)d_in[6];
  const float* proj_w = (const float*)d_in[7];
  const float* proj_b = (const float*)d_in[8];
  const float* fc1_w  = (const float*)d_in[9];
  const float* fc1_b  = (const float*)d_in[10];
  const float* fc2_w  = (const float*)d_in[11];
  const float* fc2_b  = (const float*)d_in[12];
  float* out = (float*)d_out;
  char* wsb = (char*)d_ws;
  unsigned short* lnbuf  = (unsigned short*)(wsb + 0);
  unsigned short* qkvb   = (unsigned short*)(wsb + 8388608);
  unsigned short* attnb  = (unsigned short*)(wsb + 33554432);
  unsigned short* vTb    = (unsigned short*)(wsb + 41943040);
  unsigned short* actb   = (unsigned short*)(wsb + 33554432);
  float*          h1     = (float*)(wsb + 67108864);
  unsigned short* qkvWt  = (unsigned short*)(wsb + 83886080);
  unsigned short* projWt = (unsigned short*)(wsb + 90177536);
  unsigned short* fc1Wt  = (unsigned short*)(wsb + 92274688);
  unsigned short* fc2Wt  = (unsigned short*)(wsb + 100663296);

  TD4 td;
  td.d[0] = {qkv_w,  qkvWt,  1024, 3072,  96, 0};
  td.d[1] = {proj_w, projWt, 1024, 1024,  32, 3072};
  td.d[2] = {fc1_w,  fc1Wt,  1024, 4096, 128, 4096};
  td.d[3] = {fc2_w,  fc2Wt,  4096, 1024,  32, 8192};
  transpose_all<<<12288, dim3(32, 8), 0, stream>>>(td);

  ln_kernel<<<MTOK, 256, 0, stream>>>(x, ln1_w, ln1_b, lnbuf);
  gemmBig<0, 1, 1><<<768, 256, 0, stream>>>(
      lnbuf, qkvWt, qkv_b, qkvb, nullptr, vTb, MTOK, QKV3, EMBED, 24);
  attn_kernel<<<dim3(32, 32), 256, 0, stream>>>(qkvb, vTb, attnb);
  gemm64k<1, 0><<<512, 256, 0, stream>>>(
      attnb, projWt, proj_b, x, nullptr, h1, MTOK, EMBED, EMBED, 16);
  ln_kernel<<<MTOK, 256, 0, stream>>>(h1, ln2_w, ln2_b, lnbuf);
  gemm256<1, 0><<<256, 512, 0, stream>>>(
      lnbuf, fc1Wt, fc1_b, actb, nullptr, MTOK, FFN, EMBED, 16);
  gemm64k<1, 0><<<512, 256, 0, stream>>>(
      actb, fc2Wt, fc2_b, h1, nullptr, out, MTOK, EMBED, FFN, 16);
}